// Round 3
// baseline (192.517 us; speedup 1.0000x reference)
//
#include <hip/hip_runtime.h>
#include <hip/hip_bf16.h>

typedef __attribute__((ext_vector_type(8))) __bf16 bf16x8;
typedef __attribute__((ext_vector_type(4))) float f32x4;

// Problem constants
// B=64, L=1024, H=512; M = B*L = 65536, K = 2H = 1024, N = H = 512

// ---------------------------------------------------------------------------
// Pass 0a: q[b,h] = hidden[b,:] @ W_attn[0:512, h] + b_attn[h]   (fp32)
// ---------------------------------------------------------------------------
__global__ void qk(const float* __restrict__ hidden, const float* __restrict__ W_attn,
                   const float* __restrict__ b_attn, float* __restrict__ q) {
    int idx = blockIdx.x * 256 + threadIdx.x;   // < 32768
    int b = idx >> 9;
    int h = idx & 511;
    const float* hv = hidden + b * 512;
    float acc = b_attn[h];
#pragma unroll 8
    for (int k = 0; k < 512; ++k)
        acc = fmaf(hv[k], W_attn[(size_t)k * 512 + h], acc);
    q[idx] = acc;
}

// ---------------------------------------------------------------------------
// Pass 0b: Bt[n][k] = bf16(W_attn[512 + k][n])   -> [512][1024] bf16 (B^T)
// ---------------------------------------------------------------------------
__global__ void btk(const float* __restrict__ W_attn, __bf16* __restrict__ Bt) {
    int idx = blockIdx.x * 256 + threadIdx.x;   // < 524288
    int n = idx >> 10;
    int k = idx & 1023;
    Bt[idx] = (__bf16)W_attn[(size_t)(512 + k) * 512 + n];
}

// ---------------------------------------------------------------------------
// Pass 1: fused GEMM  S = enc @ W2, logits_partial = sum_n relu(S+q)*Wv
//   A: enc [65536][1024] fp32 (converted to bf16 on the fly)
//   Bt: [512][1024] bf16 (row = output col, k-major)  -> C = A·B^T layout
//   part: [4][65536] fp32 partial logit sums (one slice per 128-col block)
// ---------------------------------------------------------------------------
__global__ __launch_bounds__(256, 2) void gemm_logits(
    const float* __restrict__ A, const __bf16* __restrict__ Bt,
    const float* __restrict__ q, const float* __restrict__ Wv,
    float* __restrict__ part)
{
    __shared__ __bf16 As[128][64];   // 16 KB
    __shared__ __bf16 Bs[128][64];   // 16 KB
    __shared__ float red[128][2];    // 1 KB epilogue reduce

    const int bid = blockIdx.x;
    // XCD-aware swizzle: 2048 blocks, 8 XCDs, 256 per XCD (bijective)
    const int swz = (bid & 7) * 256 + (bid >> 3);
    const int mt = swz >> 2;        // 0..511
    const int nt = swz & 3;         // 0..3

    const int t = threadIdx.x;
    const int lane = t & 63;
    const int wid = t >> 6;
    const int wm = wid >> 1;        // 0..1
    const int wn = wid & 1;         // 0..1

    // staging decomposition: thread -> (row = t>>3 + i*32, col8 = (t&7)*8)
    const int ar = t >> 3;
    const int ac = (t & 7) * 8;
    const float* Ag = A + (size_t)(mt * 128 + ar) * 1024 + ac;
    const __bf16* Bg = Bt + (size_t)(nt * 128 + ar) * 1024 + ac;

    f32x4 acc[4][4];
#pragma unroll
    for (int m = 0; m < 4; ++m)
#pragma unroll
        for (int n = 0; n < 4; ++n) acc[m][n] = (f32x4)0.0f;

    float4 a0[4], a1[4];
    bf16x8 bv[4];

#define LOADS(K0)                                                              \
    {                                                                          \
        _Pragma("unroll") for (int i = 0; i < 4; ++i) {                        \
            const float* p = Ag + (size_t)i * 32768 + (K0);                    \
            a0[i] = *(const float4*)p;                                         \
            a1[i] = *(const float4*)(p + 4);                                   \
            bv[i] = *(const bf16x8*)(Bg + (size_t)i * 32768 + (K0));           \
        }                                                                      \
    }

    LOADS(0)

    for (int k0 = 0; k0 < 1024; k0 += 64) {
        __syncthreads();   // previous tile's LDS reads complete
#pragma unroll
        for (int i = 0; i < 4; ++i) {
            bf16x8 v;
            v[0] = (__bf16)a0[i].x; v[1] = (__bf16)a0[i].y;
            v[2] = (__bf16)a0[i].z; v[3] = (__bf16)a0[i].w;
            v[4] = (__bf16)a1[i].x; v[5] = (__bf16)a1[i].y;
            v[6] = (__bf16)a1[i].z; v[7] = (__bf16)a1[i].w;
            *(bf16x8*)&As[ar + i * 32][ac] = v;
            *(bf16x8*)&Bs[ar + i * 32][ac] = bv[i];
        }
        __syncthreads();

        int kn = k0 + 64;
        if (kn < 1024) LOADS(kn)   // prefetch next tile during compute

        const int rsel = (lane & 15);
        const int kb = (lane >> 4) * 8;
#pragma unroll
        for (int ks = 0; ks < 2; ++ks) {
            bf16x8 af[4], bg[4];
#pragma unroll
            for (int m = 0; m < 4; ++m)
                af[m] = *(const bf16x8*)&As[wm * 64 + m * 16 + rsel][ks * 32 + kb];
#pragma unroll
            for (int n = 0; n < 4; ++n)
                bg[n] = *(const bf16x8*)&Bs[wn * 64 + n * 16 + rsel][ks * 32 + kb];
#pragma unroll
            for (int m = 0; m < 4; ++m)
#pragma unroll
                for (int n = 0; n < 4; ++n)
                    acc[m][n] = __builtin_amdgcn_mfma_f32_16x16x32_bf16(
                        af[m], bg[n], acc[m][n], 0, 0, 0);
        }
    }
#undef LOADS

    // Epilogue: logits_partial[row] = sum over this block's 128 cols of
    //           relu(acc + q[b,col]) * Wv[col]
    const int b = mt >> 3;                 // (mt*128)/1024
    const float* qb = q + b * 512;
    float qv[4], wvv[4];
#pragma unroll
    for (int n = 0; n < 4; ++n) {
        int gc = nt * 128 + wn * 64 + n * 16 + (lane & 15);
        qv[n] = qb[gc];
        wvv[n] = Wv[gc];
    }

#pragma unroll
    for (int m = 0; m < 4; ++m) {
#pragma unroll
        for (int j = 0; j < 4; ++j) {
            float s = 0.f;
#pragma unroll
            for (int n = 0; n < 4; ++n) {
                float e = acc[m][n][j] + qv[n];
                s += (e > 0.f ? e : 0.f) * wvv[n];
            }
            // reduce across the 16 lanes sharing this row (bits 0..3 of lane)
            s += __shfl_xor(s, 1);
            s += __shfl_xor(s, 2);
            s += __shfl_xor(s, 4);
            s += __shfl_xor(s, 8);
            if ((lane & 15) == 0) {
                int r = wm * 64 + m * 16 + (lane >> 4) * 4 + j;
                red[r][wn] = s;
            }
        }
    }
    __syncthreads();
    if (t < 128) {
        float v = red[t][0] + red[t][1];
        part[(size_t)nt * 65536 + (size_t)mt * 128 + t] = v;
    }
}

// ---------------------------------------------------------------------------
// Pass 2: softmax over L=1024 per batch; weights -> ws
// ---------------------------------------------------------------------------
__global__ void softmax_k(const float* __restrict__ part, float* __restrict__ w) {
    __shared__ float smx[4];
    __shared__ float ssum[4];
    int b = blockIdx.x;
    int t = threadIdx.x;
    int lane = t & 63, wid = t >> 6;
    float v[4];
    float mx = -3.0e38f;
#pragma unroll
    for (int i = 0; i < 4; ++i) {
        int l = t + i * 256;
        int o = b * 1024 + l;
        float s = part[o] + part[65536 + o] + part[131072 + o] + part[196608 + o];
        v[i] = s;
        mx = fmaxf(mx, s);
    }
#pragma unroll
    for (int off = 32; off >= 1; off >>= 1) mx = fmaxf(mx, __shfl_xor(mx, off));
    if (lane == 0) smx[wid] = mx;
    __syncthreads();
    mx = fmaxf(fmaxf(smx[0], smx[1]), fmaxf(smx[2], smx[3]));
    float e[4];
    float sum = 0.f;
#pragma unroll
    for (int i = 0; i < 4; ++i) { e[i] = __expf(v[i] - mx); sum += e[i]; }
#pragma unroll
    for (int off = 32; off >= 1; off >>= 1) sum += __shfl_xor(sum, off);
    if (lane == 0) ssum[wid] = sum;
    __syncthreads();
    float inv = 1.f / (ssum[0] + ssum[1] + ssum[2] + ssum[3]);
#pragma unroll
    for (int i = 0; i < 4; ++i) w[b * 1024 + t + i * 256] = e[i] * inv;
}

// ---------------------------------------------------------------------------
// Pass 3: partial context: ctxp[lc][b][e] = sum_{l in chunk lc} w[b,l]*enc[b,l,e]
// ---------------------------------------------------------------------------
__global__ void ctx_partial(const float* __restrict__ enc, const float* __restrict__ w,
                            float* __restrict__ ctxp) {
    int blk = blockIdx.x;   // 0..511
    int b = blk >> 3;
    int lc = blk & 7;
    int t = threadIdx.x;    // 256
    __shared__ float wl[128];
    if (t < 128) wl[t] = w[b * 1024 + lc * 128 + t];
    __syncthreads();
    float4 acc = {0.f, 0.f, 0.f, 0.f};
    const float* base = enc + ((size_t)(b * 1024 + lc * 128)) * 1024 + t * 4;
    for (int l = 0; l < 128; ++l) {
        float4 v = *(const float4*)(base + (size_t)l * 1024);
        float s = wl[l];
        acc.x += s * v.x; acc.y += s * v.y; acc.z += s * v.z; acc.w += s * v.w;
    }
    *(float4*)(ctxp + (size_t)(lc * 64 + b) * 1024 + t * 4) = acc;
}

// ---------------------------------------------------------------------------
// Pass 4: out[b][e] = sum_lc ctxp[lc][b][e]
// ---------------------------------------------------------------------------
__global__ void ctx_sum(const float* __restrict__ ctxp, float* __restrict__ out) {
    int idx = blockIdx.x * 256 + threadIdx.x;   // < 16384 (float4 each)
    float4 a = {0.f, 0.f, 0.f, 0.f};
#pragma unroll
    for (int lc = 0; lc < 8; ++lc) {
        float4 v = *(const float4*)(ctxp + (size_t)lc * 65536 + (size_t)idx * 4);
        a.x += v.x; a.y += v.y; a.z += v.z; a.w += v.w;
    }
    *(float4*)(out + (size_t)idx * 4) = a;
}

// ---------------------------------------------------------------------------
extern "C" void kernel_launch(void* const* d_in, const int* in_sizes, int n_in,
                              void* d_out, int out_size, void* d_ws, size_t ws_size,
                              hipStream_t stream) {
    const float* hidden = (const float*)d_in[0];
    const float* enc    = (const float*)d_in[1];
    const float* W_attn = (const float*)d_in[2];
    const float* b_attn = (const float*)d_in[3];
    const float* W_v    = (const float*)d_in[4];
    float* out = (float*)d_out;

    char* ws = (char*)d_ws;
    float*  q    = (float*)(ws + 0);          // 128 KB  [64][512]
    __bf16* Bt   = (__bf16*)(ws + 131072);    // 1 MB    [512][1024]
    float*  part = (float*)(ws + 1179648);    // 1 MB    [4][65536]
    float*  wts  = (float*)(ws + 2228224);    // 256 KB  [64][1024]
    float*  ctxp = (float*)(ws + 2490368);    // 2 MB    [8][64][1024]

    qk<<<128, 256, 0, stream>>>(hidden, W_attn, b_attn, q);
    btk<<<2048, 256, 0, stream>>>(W_attn, Bt);
    gemm_logits<<<2048, 256, 0, stream>>>(enc, Bt, q, W_v, part);
    softmax_k<<<64, 256, 0, stream>>>(part, wts);
    ctx_partial<<<512, 256, 0, stream>>>(enc, wts, ctxp);
    ctx_sum<<<64, 256, 0, stream>>>(ctxp, out);
}

// Round 4
// 177.008 us; speedup vs baseline: 1.0876x; 1.0876x over previous
//
#include <hip/hip_runtime.h>
#include <hip/hip_bf16.h>

typedef __attribute__((ext_vector_type(8))) __bf16 bf16x8;
typedef __attribute__((ext_vector_type(4))) float f32x4;

// Problem constants
// B=64, L=1024, H=512; M = B*L = 65536, K = 2H = 1024, N = H = 512

// ---------------------------------------------------------------------------
// Pass 0a: q[b,h] = hidden[b,:] @ W_attn[0:512, h] + b_attn[h]   (fp32)
// ---------------------------------------------------------------------------
__global__ void qk(const float* __restrict__ hidden, const float* __restrict__ W_attn,
                   const float* __restrict__ b_attn, float* __restrict__ q) {
    int idx = blockIdx.x * 256 + threadIdx.x;   // < 32768
    int b = idx >> 9;
    int h = idx & 511;
    const float* hv = hidden + b * 512;
    float acc = b_attn[h];
#pragma unroll 8
    for (int k = 0; k < 512; ++k)
        acc = fmaf(hv[k], W_attn[(size_t)k * 512 + h], acc);
    q[idx] = acc;
}

// ---------------------------------------------------------------------------
// Pass 0b: Bt[n][k] = bf16(W_attn[512 + k][n])   -> [512][1024] bf16 (B^T)
// ---------------------------------------------------------------------------
__global__ void btk(const float* __restrict__ W_attn, __bf16* __restrict__ Bt) {
    int idx = blockIdx.x * 256 + threadIdx.x;   // < 524288
    int n = idx >> 10;
    int k = idx & 1023;
    Bt[idx] = (__bf16)W_attn[(size_t)(512 + k) * 512 + n];
}

// ---------------------------------------------------------------------------
// Pass 1: fused GEMM  S = enc @ W2, logits_partial = sum_n relu(S+q)*Wv
//   A: enc [65536][1024] fp32 (converted to bf16 on the fly)
//   Bt: [512][1024] bf16 (row = output col, k-major)  -> C = A·B^T layout
//   part: [4][65536] fp32 partial logit sums (one slice per 128-col block)
//   LDS tiles use T2 XOR-swizzle: 16B slot ^= (row&7); kills the 16-way
//   bank conflict on the stride-128B fragment reads (R3: 2.5e7 conflicts).
// ---------------------------------------------------------------------------
__global__ __launch_bounds__(256, 2) void gemm_logits(
    const float* __restrict__ A, const __bf16* __restrict__ Bt,
    const float* __restrict__ q, const float* __restrict__ Wv,
    float* __restrict__ part)
{
    __shared__ __bf16 As[128][64];   // 16 KB
    __shared__ __bf16 Bs[128][64];   // 16 KB
    __shared__ float red[128][2];    // 1 KB epilogue reduce

    const int bid = blockIdx.x;
    // XCD-aware swizzle: 2048 blocks, 8 XCDs, 256 per XCD (bijective)
    const int swz = (bid & 7) * 256 + (bid >> 3);
    const int mt = swz >> 2;        // 0..511
    const int nt = swz & 3;         // 0..3

    const int t = threadIdx.x;
    const int lane = t & 63;
    const int wid = t >> 6;
    const int wm = wid >> 1;        // 0..1
    const int wn = wid & 1;         // 0..1

    // staging decomposition: thread -> (row = t>>3 + i*32, col8 = (t&7)*8)
    const int ar = t >> 3;
    const int ac = (t & 7) * 8;
    // swizzled write column: (ar+i*32)&7 == ar&7, so constant per thread
    const int acw = ac ^ ((ar & 7) << 3);
    const float* Ag = A + (size_t)(mt * 128 + ar) * 1024 + ac;
    const __bf16* Bg = Bt + (size_t)(nt * 128 + ar) * 1024 + ac;

    f32x4 acc[4][4];
#pragma unroll
    for (int m = 0; m < 4; ++m)
#pragma unroll
        for (int n = 0; n < 4; ++n) acc[m][n] = (f32x4)0.0f;

    float4 a0[4], a1[4];
    bf16x8 bv[4];

#define LOADS(K0)                                                              \
    {                                                                          \
        _Pragma("unroll") for (int i = 0; i < 4; ++i) {                        \
            const float* p = Ag + (size_t)i * 32768 + (K0);                    \
            a0[i] = *(const float4*)p;                                         \
            a1[i] = *(const float4*)(p + 4);                                   \
            bv[i] = *(const bf16x8*)(Bg + (size_t)i * 32768 + (K0));           \
        }                                                                      \
    }

    LOADS(0)

    for (int k0 = 0; k0 < 1024; k0 += 64) {
        __syncthreads();   // previous tile's LDS reads complete
#pragma unroll
        for (int i = 0; i < 4; ++i) {
            bf16x8 v;
            v[0] = (__bf16)a0[i].x; v[1] = (__bf16)a0[i].y;
            v[2] = (__bf16)a0[i].z; v[3] = (__bf16)a0[i].w;
            v[4] = (__bf16)a1[i].x; v[5] = (__bf16)a1[i].y;
            v[6] = (__bf16)a1[i].z; v[7] = (__bf16)a1[i].w;
            *(bf16x8*)&As[ar + i * 32][acw] = v;
            *(bf16x8*)&Bs[ar + i * 32][acw] = bv[i];
        }
        __syncthreads();

        int kn = k0 + 64;
        if (kn < 1024) LOADS(kn)   // prefetch next tile during compute

        const int rsel = (lane & 15);
        const int kb = (lane >> 4) * 8;
        // read-side swizzle: row&7 == rsel&7 (wm*64, m*16 are multiples of 8)
        const int rsw = (rsel & 7) << 3;
#pragma unroll
        for (int ks = 0; ks < 2; ++ks) {
            bf16x8 af[4], bg[4];
#pragma unroll
            for (int m = 0; m < 4; ++m)
                af[m] = *(const bf16x8*)&As[wm * 64 + m * 16 + rsel][(ks * 32 + kb) ^ rsw];
#pragma unroll
            for (int n = 0; n < 4; ++n)
                bg[n] = *(const bf16x8*)&Bs[wn * 64 + n * 16 + rsel][(ks * 32 + kb) ^ rsw];
#pragma unroll
            for (int m = 0; m < 4; ++m)
#pragma unroll
                for (int n = 0; n < 4; ++n)
                    acc[m][n] = __builtin_amdgcn_mfma_f32_16x16x32_bf16(
                        af[m], bg[n], acc[m][n], 0, 0, 0);
        }
    }
#undef LOADS

    // Epilogue: logits_partial[row] = sum over this block's 128 cols of
    //           relu(acc + q[b,col]) * Wv[col]
    const int b = mt >> 3;                 // (mt*128)/1024
    const float* qb = q + b * 512;
    float qv[4], wvv[4];
#pragma unroll
    for (int n = 0; n < 4; ++n) {
        int gc = nt * 128 + wn * 64 + n * 16 + (lane & 15);
        qv[n] = qb[gc];
        wvv[n] = Wv[gc];
    }

#pragma unroll
    for (int m = 0; m < 4; ++m) {
#pragma unroll
        for (int j = 0; j < 4; ++j) {
            float s = 0.f;
#pragma unroll
            for (int n = 0; n < 4; ++n) {
                float e = acc[m][n][j] + qv[n];
                s += (e > 0.f ? e : 0.f) * wvv[n];
            }
            // reduce across the 16 lanes sharing this row (bits 0..3 of lane)
            s += __shfl_xor(s, 1);
            s += __shfl_xor(s, 2);
            s += __shfl_xor(s, 4);
            s += __shfl_xor(s, 8);
            if ((lane & 15) == 0) {
                int r = wm * 64 + m * 16 + (lane >> 4) * 4 + j;
                red[r][wn] = s;
            }
        }
    }
    __syncthreads();
    if (t < 128) {
        float v = red[t][0] + red[t][1];
        part[(size_t)nt * 65536 + (size_t)mt * 128 + t] = v;
    }
}

// ---------------------------------------------------------------------------
// Pass 2: softmax over L=1024 per batch; weights -> ws
// ---------------------------------------------------------------------------
__global__ void softmax_k(const float* __restrict__ part, float* __restrict__ w) {
    __shared__ float smx[4];
    __shared__ float ssum[4];
    int b = blockIdx.x;
    int t = threadIdx.x;
    int lane = t & 63, wid = t >> 6;
    float v[4];
    float mx = -3.0e38f;
#pragma unroll
    for (int i = 0; i < 4; ++i) {
        int l = t + i * 256;
        int o = b * 1024 + l;
        float s = part[o] + part[65536 + o] + part[131072 + o] + part[196608 + o];
        v[i] = s;
        mx = fmaxf(mx, s);
    }
#pragma unroll
    for (int off = 32; off >= 1; off >>= 1) mx = fmaxf(mx, __shfl_xor(mx, off));
    if (lane == 0) smx[wid] = mx;
    __syncthreads();
    mx = fmaxf(fmaxf(smx[0], smx[1]), fmaxf(smx[2], smx[3]));
    float e[4];
    float sum = 0.f;
#pragma unroll
    for (int i = 0; i < 4; ++i) { e[i] = __expf(v[i] - mx); sum += e[i]; }
#pragma unroll
    for (int off = 32; off >= 1; off >>= 1) sum += __shfl_xor(sum, off);
    if (lane == 0) ssum[wid] = sum;
    __syncthreads();
    float inv = 1.f / (ssum[0] + ssum[1] + ssum[2] + ssum[3]);
#pragma unroll
    for (int i = 0; i < 4; ++i) w[b * 1024 + t + i * 256] = e[i] * inv;
}

// ---------------------------------------------------------------------------
// Pass 3: partial context: ctxp[lc][b][e] = sum_{l in chunk lc} w[b,l]*enc[b,l,e]
// ---------------------------------------------------------------------------
__global__ void ctx_partial(const float* __restrict__ enc, const float* __restrict__ w,
                            float* __restrict__ ctxp) {
    int blk = blockIdx.x;   // 0..511
    int b = blk >> 3;
    int lc = blk & 7;
    int t = threadIdx.x;    // 256
    __shared__ float wl[128];
    if (t < 128) wl[t] = w[b * 1024 + lc * 128 + t];
    __syncthreads();
    float4 acc = {0.f, 0.f, 0.f, 0.f};
    const float* base = enc + ((size_t)(b * 1024 + lc * 128)) * 1024 + t * 4;
    for (int l = 0; l < 128; ++l) {
        float4 v = *(const float4*)(base + (size_t)l * 1024);
        float s = wl[l];
        acc.x += s * v.x; acc.y += s * v.y; acc.z += s * v.z; acc.w += s * v.w;
    }
    *(float4*)(ctxp + (size_t)(lc * 64 + b) * 1024 + t * 4) = acc;
}

// ---------------------------------------------------------------------------
// Pass 4: out[b][e] = sum_lc ctxp[lc][b][e]
// ---------------------------------------------------------------------------
__global__ void ctx_sum(const float* __restrict__ ctxp, float* __restrict__ out) {
    int idx = blockIdx.x * 256 + threadIdx.x;   // < 16384 (float4 each)
    float4 a = {0.f, 0.f, 0.f, 0.f};
#pragma unroll
    for (int lc = 0; lc < 8; ++lc) {
        float4 v = *(const float4*)(ctxp + (size_t)lc * 65536 + (size_t)idx * 4);
        a.x += v.x; a.y += v.y; a.z += v.z; a.w += v.w;
    }
    *(float4*)(out + (size_t)idx * 4) = a;
}

// ---------------------------------------------------------------------------
extern "C" void kernel_launch(void* const* d_in, const int* in_sizes, int n_in,
                              void* d_out, int out_size, void* d_ws, size_t ws_size,
                              hipStream_t stream) {
    const float* hidden = (const float*)d_in[0];
    const float* enc    = (const float*)d_in[1];
    const float* W_attn = (const float*)d_in[2];
    const float* b_attn = (const float*)d_in[3];
    const float* W_v    = (const float*)d_in[4];
    float* out = (float*)d_out;

    char* ws = (char*)d_ws;
    float*  q    = (float*)(ws + 0);          // 128 KB  [64][512]
    __bf16* Bt   = (__bf16*)(ws + 131072);    // 1 MB    [512][1024]
    float*  part = (float*)(ws + 1179648);    // 1 MB    [4][65536]
    float*  wts  = (float*)(ws + 2228224);    // 256 KB  [64][1024]
    float*  ctxp = (float*)(ws + 2490368);    // 2 MB    [8][64][1024]

    qk<<<128, 256, 0, stream>>>(hidden, W_attn, b_attn, q);
    btk<<<2048, 256, 0, stream>>>(W_attn, Bt);
    gemm_logits<<<2048, 256, 0, stream>>>(enc, Bt, q, W_v, part);
    softmax_k<<<64, 256, 0, stream>>>(part, wts);
    ctx_partial<<<512, 256, 0, stream>>>(enc, wts, ctxp);
    ctx_sum<<<64, 256, 0, stream>>>(ctxp, out);
}